// Round 9
// baseline (1444.036 us; speedup 1.0000x reference)
//
#include <hip/hip_runtime.h>
#include <hip/hip_bf16.h>

typedef unsigned short u16;
typedef __attribute__((ext_vector_type(8))) __bf16 bf16x8;
typedef __attribute__((ext_vector_type(8))) short short8;
typedef __attribute__((ext_vector_type(4))) float f32x4;
typedef __attribute__((ext_vector_type(4))) unsigned int u32x4;

#define BB 4096
#define TT 19
#define INP 17
#define HH 1024
#define NE 4224          // 4096 gate entries + 128 proj entries
#define NT_PROJ 32       // nt index of the projection tile

__device__ __forceinline__ u16 f2bfu(float f) {
    __hip_bfloat16 b = __float2bfloat16(f);
    return __builtin_bit_cast(unsigned short, b);
}
__device__ __forceinline__ float fast_sigmoid(float x) {
    return 1.f / (1.f + __expf(-x));
}
__device__ __forceinline__ float fast_tanh(float x) {
    float e = __expf(2.f * x);
    return (e - 1.f) / (e + 1.f);
}
// 16B-slot swizzle within a 32-elem row (involution)
__device__ __forceinline__ int fsw(int r) { return (r ^ (r >> 2)) & 3; }

// async 16B global -> LDS (linear dest: wave-uniform base + lane*16)
__device__ __forceinline__ void cp16(void* l, const void* g) {
    __builtin_amdgcn_global_load_lds(
        (const __attribute__((address_space(1))) unsigned int*)g,
        (__attribute__((address_space(3))) unsigned int*)l, 16, 0, 0);
}

// ---------------- prep kernels ----------------
// wperm[NE][HH]: permuted W rows. grid MUST be 2112 (2112*256*8 == NE*HH).
__global__ void prep_wperm(const float* __restrict__ Whh, const float* __restrict__ Wlin,
                           u16* __restrict__ wperm) {
    size_t idx = ((size_t)blockIdx.x * 256 + threadIdx.x) * 8;
    int R = (int)(idx >> 10);
    int k = (int)(idx & 1023);
    int nt = R >> 7, r = R & 127;
    const float* src = nullptr;
    if (nt < NT_PROJ) {
        int gate = (r & 63) >> 4;
        int hcol = nt * 32 + ((r >> 6) << 4) + (r & 15);
        src = Whh + ((size_t)(gate * HH + hcol)) * HH + k;
    } else if (r < INP) {
        src = Wlin + (size_t)r * HH + k;
    }
#pragma unroll
    for (int e = 0; e < 8; ++e) wperm[idx + e] = src ? f2bfu(src[e]) : (u16)0;
}

// wxperm[NE][32]: permuted, padded W_ih rows. grid 528 (528*256 == NE*32).
__global__ void prep_wx(const float* __restrict__ Wih, u16* __restrict__ wxperm) {
    int idx = blockIdx.x * 256 + threadIdx.x;
    int R = idx >> 5, k = idx & 31;
    int nt = R >> 7, r = R & 127;
    u16 v = 0;
    if (nt < NT_PROJ && k < INP) {
        int gate = (r & 63) >> 4;
        int hcol = nt * 32 + ((r >> 6) << 4) + (r & 15);
        v = f2bfu(Wih[(size_t)(gate * HH + hcol) * INP + k]);
    }
    wxperm[idx] = v;
}

// bias[4096] = b_ih + b_hh. grid 16.
__global__ void prep_bias(const float* __restrict__ bih, const float* __restrict__ bhh,
                          float* __restrict__ bias) {
    int idx = blockIdx.x * 256 + threadIdx.x;
    bias[idx] = bih[idx] + bhh[idx];
}

// xpad[t][b][32]. grid 9728 (9728*256 == 19*4096*32).
__global__ void prep_x(const float* __restrict__ x, u16* __restrict__ xpad) {
    int idx = blockIdx.x * 256 + threadIdx.x;
    int c = idx & 31;
    int rb = idx >> 5;       // t*4096 + b
    int t = rb >> 12;
    int b = rb & 4095;
    xpad[idx] = (c < INP) ? f2bfu(x[((size_t)b * TT + t) * INP + c]) : (u16)0;
}

// ---------------- fused step kernel (2-phase double-buffered GEMM) --------
// grid 1056 = 32 mt x 33 nt, 256 threads (4 waves, 2x2 quadrants of 64x64).
// C = [x_pad | h] @ [Wih_perm | W_perm]^T + bias   (128 rows x 128 entries)
// K pipeline: 33 steps (x + 32 h-chunks), prefetch step s+1 into buf^1 while
// computing step s; ONE barrier per step (its implicit vmcnt drain covers
// the prefetch). nt < 32: LSTM cell epilogue; nt == 32: out_{t-1} proj tile.
__global__ __launch_bounds__(256, 4) void lstm_step(
    const u16* __restrict__ h_in, u16* __restrict__ h_out,
    float* __restrict__ c_buf, const u16* __restrict__ wperm,
    const u16* __restrict__ wxperm, const float* __restrict__ bias,
    const u16* __restrict__ xpad, const float* __restrict__ blin,
    float* __restrict__ outp, float* __restrict__ h_fin,
    int t, int is_last, int proj_force)
{
    __shared__ u16 sA[2][128 * 32];   // 2 x 8 KB
    __shared__ u16 sB[2][128 * 32];   // 2 x 8 KB

    const int tid = threadIdx.x;
    const int lane = tid & 63;
    const int wv = tid >> 6;
    const int qr = wv >> 1, qc = wv & 1;
    const int r16 = lane & 15, s4 = lane >> 4;

    int mt, nt;
    if (proj_force) { mt = blockIdx.x; nt = NT_PROJ; }
    else {
        int v = (blockIdx.x & 7) * 132 + (blockIdx.x >> 3);  // XCD-chunked, bijective
        nt = v >> 5; mt = v & 31;
    }
    const int m0 = mt * 128;
    if (nt == NT_PROJ && t == 0) return;   // uniform early-out, before any barrier

    // staging: thread covers slots tid and tid+256; slot -> (row=slot>>2, chunk=slot&3)
    const int row0 = tid >> 2, c0 = tid & 3;
    const int row1 = row0 + 64;
    const int xo0 = (c0 ^ fsw(row0)) * 8;
    const int xo1 = (c0 ^ fsw(row1)) * 8;
    const size_t R0 = (size_t)nt * 128;

    // hoisted global source pointers (stageH adds kc only)
    const u16* ga0 = h_in + (size_t)(m0 + row0) * HH + xo0;
    const u16* ga1 = h_in + (size_t)(m0 + row1) * HH + xo1;
    const u16* gb0 = wperm + (R0 + row0) * HH + xo0;
    const u16* gb1 = wperm + (R0 + row1) * HH + xo1;

    // acc init with bias (col constant across the 4 row-regs of a C/D frag)
    f32x4 acc[4][4];
    if (nt < NT_PROJ) {
        const int n = nt * 32 + qc * 16 + r16;
#pragma unroll
        for (int g = 0; g < 4; ++g) {
            float bv = bias[g * HH + n];
#pragma unroll
            for (int mf = 0; mf < 4; ++mf) acc[mf][g] = (f32x4){bv, bv, bv, bv};
        }
    } else {
#pragma unroll
        for (int nf = 0; nf < 4; ++nf) {
            int e = qc * 64 + nf * 16 + r16;
            float bv = (e < INP) ? blin[e] : 0.f;
#pragma unroll
            for (int mf = 0; mf < 4; ++mf) acc[mf][nf] = (f32x4){bv, bv, bv, bv};
        }
    }

    // fragment read offsets (u16 elem index, swizzled)
    int aoff[4], boff[4];
#pragma unroll
    for (int mf = 0; mf < 4; ++mf) {
        int r = qr * 64 + mf * 16 + r16;
        aoff[mf] = r * 32 + ((s4 ^ fsw(r)) * 8);
    }
#pragma unroll
    for (int nf = 0; nf < 4; ++nf) {
        int r = qc * 64 + nf * 16 + r16;
        boff[nf] = r * 32 + ((s4 ^ fsw(r)) * 8);
    }

    // ---- prologue: stage step 0 (x @ Wih^T, K padded 17->32) into buf 0 ----
    cp16(&sA[0][tid * 8],         xpad + ((size_t)t * BB + m0 + row0) * 32 + xo0);
    cp16(&sA[0][(tid + 256) * 8], xpad + ((size_t)t * BB + m0 + row1) * 32 + xo1);
    cp16(&sB[0][tid * 8],         wxperm + (R0 + row0) * 32 + xo0);
    cp16(&sB[0][(tid + 256) * 8], wxperm + (R0 + row1) * 32 + xo1);
    __syncthreads();   // drains vmcnt -> step 0 resident

    // ---- 2-phase pipeline: 33 steps total; loop s computes step s, stages s+1
#pragma unroll 2
    for (int s = 0; s < 32; ++s) {
        const int kc = s * 32;            // K-offset of step s+1
        const int nb = (s + 1) & 1;       // buffer for step s+1
        const int cb = s & 1;             // buffer for step s
        cp16(&sA[nb][tid * 8],         ga0 + kc);
        cp16(&sA[nb][(tid + 256) * 8], ga1 + kc);
        cp16(&sB[nb][tid * 8],         gb0 + kc);
        cp16(&sB[nb][(tid + 256) * 8], gb1 + kc);

        bf16x8 a[4], b[4];
#pragma unroll
        for (int mf = 0; mf < 4; ++mf) a[mf] = __builtin_bit_cast(bf16x8, *(const short8*)&sA[cb][aoff[mf]]);
#pragma unroll
        for (int nf = 0; nf < 4; ++nf) b[nf] = __builtin_bit_cast(bf16x8, *(const short8*)&sB[cb][boff[nf]]);
#pragma unroll
        for (int nf = 0; nf < 4; ++nf)
#pragma unroll
            for (int mf = 0; mf < 4; ++mf)
                acc[mf][nf] = __builtin_amdgcn_mfma_f32_16x16x32_bf16(a[mf], b[nf], acc[mf][nf], 0, 0, 0);

        __syncthreads();  // drains prefetch vmcnt; protects buf reuse next iter
    }
    {   // final step 32 (kc = 992) sits in buf 0
        bf16x8 a[4], b[4];
#pragma unroll
        for (int mf = 0; mf < 4; ++mf) a[mf] = __builtin_bit_cast(bf16x8, *(const short8*)&sA[0][aoff[mf]]);
#pragma unroll
        for (int nf = 0; nf < 4; ++nf) b[nf] = __builtin_bit_cast(bf16x8, *(const short8*)&sB[0][boff[nf]]);
#pragma unroll
        for (int nf = 0; nf < 4; ++nf)
#pragma unroll
            for (int mf = 0; mf < 4; ++mf)
                acc[mf][nf] = __builtin_amdgcn_mfma_f32_16x16x32_bf16(a[mf], b[nf], acc[mf][nf], 0, 0, 0);
    }

    // ---- epilogue ----
    if (nt < NT_PROJ) {
        const int n = nt * 32 + qc * 16 + r16;
#pragma unroll
        for (int mf = 0; mf < 4; ++mf)
#pragma unroll
            for (int j = 0; j < 4; ++j) {
                int row = m0 + qr * 64 + mf * 16 + s4 * 4 + j;
                float iv = fast_sigmoid(acc[mf][0][j]);
                float fv = fast_sigmoid(acc[mf][1][j]);
                float gv = fast_tanh(acc[mf][2][j]);
                float ov = fast_sigmoid(acc[mf][3][j]);
                size_t ci = (size_t)row * HH + n;
                float cold = __builtin_nontemporal_load(&c_buf[ci]);
                float cnew = fv * cold + iv * gv;
                float hnew = ov * fast_tanh(cnew);
                __builtin_nontemporal_store(cnew, &c_buf[ci]);
                h_out[ci] = f2bfu(hnew);
                if (is_last) __builtin_nontemporal_store(hnew, &h_fin[ci]);
            }
    } else {
#pragma unroll
        for (int mf = 0; mf < 4; ++mf)
#pragma unroll
            for (int j = 0; j < 4; ++j) {
                int row = m0 + qr * 64 + mf * 16 + s4 * 4 + j;
#pragma unroll
                for (int nf = 0; nf < 4; ++nf) {
                    int e = qc * 64 + nf * 16 + r16;
                    if (e < INP)
                        __builtin_nontemporal_store(
                            acc[mf][nf][j],
                            &outp[((size_t)row * TT + (t - 1)) * INP + e]);
                }
            }
    }
}

// ---------------- launch ----------------
extern "C" void kernel_launch(void* const* d_in, const int* in_sizes, int n_in,
                              void* d_out, int out_size, void* d_ws, size_t ws_size,
                              hipStream_t stream)
{
    const float* x    = (const float*)d_in[0];
    const float* Wih  = (const float*)d_in[1];
    const float* Whh  = (const float*)d_in[2];
    const float* bih  = (const float*)d_in[3];
    const float* bhh  = (const float*)d_in[4];
    const float* Wlin = (const float*)d_in[5];
    const float* blin = (const float*)d_in[6];
    float* out = (float*)d_out;

    char* ws = (char*)d_ws;
    u16* hb0     = (u16*)(ws);                     //  8,388,608 B
    u16* hb1     = (u16*)(ws +  8388608);          //  8,388,608 B
    u16* xpad    = (u16*)(ws + 16777216);          //  5,242,880 B (20 t-slots)
    u16* wperm   = (u16*)(ws + 22020096);          //  8,650,752 B (4224 x 1024)
    u16* wxperm  = (u16*)(ws + 30670848);          //    270,336 B (4224 x 32)
    float* bias  = (float*)(ws + 30941184);        //     16,384 B

    float* h_fin = out + (size_t)BB * TT * INP;    // h_fin region
    float* c_buf = h_fin + (size_t)BB * HH;        // c_fin region = c state

    hipMemsetAsync(hb0, 0, (size_t)BB * HH * sizeof(u16), stream);
    hipMemsetAsync(c_buf, 0, (size_t)BB * HH * sizeof(float), stream);
    hipMemsetAsync((char*)xpad + (size_t)19 * BB * 32 * 2, 0, BB * 32 * 2, stream);

    prep_wperm<<<2112, 256, 0, stream>>>(Whh, Wlin, wperm);
    prep_wx<<<528, 256, 0, stream>>>(Wih, wxperm);
    prep_bias<<<16, 256, 0, stream>>>(bih, bhh, bias);
    prep_x<<<9728, 256, 0, stream>>>(x, xpad);

    for (int t = 0; t < TT; ++t) {
        const u16* hin = (t & 1) ? hb1 : hb0;
        u16* hout = (t & 1) ? hb0 : hb1;
        lstm_step<<<1056, 256, 0, stream>>>(
            hin, hout, c_buf, wperm, wxperm, bias, xpad, blin, out,
            h_fin, t, (t == TT - 1) ? 1 : 0, 0);
    }
    // tail: out_18 = h_19 @ W_lin^T + b_lin  (h_19 is in hb1 after t=18)
    lstm_step<<<32, 256, 0, stream>>>(
        hb1, hb0, c_buf, wperm, wxperm, bias, xpad, blin, out,
        h_fin, TT, 0, 1);
}

// Round 10
// 1338.424 us; speedup vs baseline: 1.0789x; 1.0789x over previous
//
#include <hip/hip_runtime.h>
#include <hip/hip_bf16.h>

typedef unsigned short u16;
typedef __attribute__((ext_vector_type(8))) __bf16 bf16x8;
typedef __attribute__((ext_vector_type(8))) short short8;
typedef __attribute__((ext_vector_type(4))) float f32x4;
typedef __attribute__((ext_vector_type(4))) unsigned int u32x4;

#define BB 4096
#define TT 19
#define INP 17
#define HH 1024
#define NE 4128          // 4096 permuted gate entries + 32 proj rows
#define NT_PROJ 15       // proj rows are staged/used by nt==15 blocks

__device__ __forceinline__ u16 f2bfu(float f) {
    __hip_bfloat16 b = __float2bfloat16(f);
    return __builtin_bit_cast(unsigned short, b);
}
__device__ __forceinline__ float fast_sigmoid(float x) {
    return 1.f / (1.f + __expf(-x));
}
__device__ __forceinline__ float fast_tanh(float x) {
    float e = __expf(2.f * x);
    return (e - 1.f) / (e + 1.f);
}
__device__ __forceinline__ bf16x8 ld16(const u16* p) {
    return __builtin_bit_cast(bf16x8, *(const u32x4*)p);
}
// 16B-slot swizzle within a 32-elem row (involution), r8-validated
__device__ __forceinline__ int fsw(int r) { return (r ^ (r >> 2)) & 3; }

// async 16B global -> LDS (linear dest)
__device__ __forceinline__ void cp16(void* l, const void* g) {
    __builtin_amdgcn_global_load_lds(
        (const __attribute__((address_space(1))) unsigned int*)g,
        (__attribute__((address_space(3))) unsigned int*)l, 16, 0, 0);
}

// ---------------- prep kernels ----------------
// wperm[NE][HH]. Entry r of tile nt: gate=(r>>4)&3, hcol=nt*64+(r>>6)*16+(r&15).
// Rows 4096..4127: W_lin rows 0..16, rest zero. grid MUST be 2064.
__global__ void prep_wperm(const float* __restrict__ Whh, const float* __restrict__ Wlin,
                           u16* __restrict__ wperm) {
    size_t idx = ((size_t)blockIdx.x * 256 + threadIdx.x) * 8;
    int R = (int)(idx >> 10);
    int k = (int)(idx & 1023);
    const float* src = nullptr;
    if (R < 4096) {
        int nt = R >> 8, r = R & 255;
        int qn = r >> 6, nf = (r >> 4) & 3, cj = r & 15;
        int hcol = nt * 64 + qn * 16 + cj;
        src = Whh + ((size_t)(nf * HH + hcol)) * HH + k;
    } else if (R - 4096 < INP) {
        src = Wlin + (size_t)(R - 4096) * HH + k;
    }
#pragma unroll
    for (int e = 0; e < 8; ++e) wperm[idx + e] = src ? f2bfu(src[e]) : (u16)0;
}

// wxperm[NE][32]: same row permutation for W_ih (K padded 17->32). grid 516.
__global__ void prep_wx(const float* __restrict__ Wih, u16* __restrict__ wxperm) {
    int idx = blockIdx.x * 256 + threadIdx.x;
    int R = idx >> 5, k = idx & 31;
    u16 v = 0;
    if (R < 4096 && k < INP) {
        int nt = R >> 8, r = R & 255;
        int qn = r >> 6, nf = (r >> 4) & 3, cj = r & 15;
        int hcol = nt * 64 + qn * 16 + cj;
        v = f2bfu(Wih[(size_t)(nf * HH + hcol) * INP + k]);
    }
    wxperm[idx] = v;
}

// bias[4096] = b_ih + b_hh. grid 16.
__global__ void prep_bias(const float* __restrict__ bih, const float* __restrict__ bhh,
                          float* __restrict__ bias) {
    int idx = blockIdx.x * 256 + threadIdx.x;
    bias[idx] = bih[idx] + bhh[idx];
}

// xpad[t][b][32]. grid 9728.
__global__ void prep_x(const float* __restrict__ x, u16* __restrict__ xpad) {
    int idx = blockIdx.x * 256 + threadIdx.x;
    int c = idx & 31;
    int rb = idx >> 5;
    int t = rb >> 12;
    int b = rb & 4095;
    xpad[idx] = (c < INP) ? f2bfu(x[((size_t)b * TT + t) * INP + c]) : (u16)0;
}

// ------------- fused step kernel: 256x256 tile, 2-phase dbuf -------------
// grid 256 = 16 mt x 16 nt (XCD 2D-chunked), 512 threads = 8 waves (2qr x 4qn).
// Wave owns 128 rows (8 mf) x 64 entries (4 nf = 4 gates of hcols nt*64+qn*16+..).
// K pipeline: 33 tiles (x + 32 h), BK=32, double-buffered, one barrier/tile.
// nt==15 blocks: waves qn<2 also accumulate proj (out_{t-1} = h_t @ W_lin^T)
// via one extra B-fragment loaded straight from L2 (W_lin hot, 34 KB).
__global__ __launch_bounds__(512, 2) void lstm_step(
    const u16* __restrict__ h_in, u16* __restrict__ h_out,
    float* __restrict__ c_buf, const u16* __restrict__ wperm,
    const u16* __restrict__ wxperm, const float* __restrict__ bias,
    const u16* __restrict__ xpad, const float* __restrict__ blin,
    float* __restrict__ outp, float* __restrict__ h_fin,
    int t, int is_last, int tail)
{
    __shared__ u16 sA[2][256 * 32];   // 2 x 16 KB
    __shared__ u16 sB[2][256 * 32];   // 2 x 16 KB  (total 64 KB static)

    const int tid = threadIdx.x;
    const int lane = tid & 63;
    const int wv = tid >> 6;          // 0..7
    const int qr = wv >> 2;           // 0..1  (row half)
    const int qn = wv & 3;            // 0..3  (entry quarter)
    const int r16 = lane & 15, s4 = lane >> 4;

    int mt, nt;
    if (tail) { mt = blockIdx.x; nt = NT_PROJ; }
    else {
        const int xcd = blockIdx.x & 7, local = blockIdx.x >> 3;   // 2D XCD chunk
        mt = (xcd >> 2) * 8 + (local & 7);
        nt = (xcd & 3) * 4 + (local >> 3);
    }
    const int m0 = mt * 256;
    const size_t R0 = (size_t)nt * 256;
    const bool my_proj = (nt == NT_PROJ) && (qn < 2);

    // staging: thread covers slots tid and tid+512; slot -> (row=slot>>2, c=slot&3)
    const int row0 = tid >> 2, c0 = tid & 3;
    const int row1 = row0 + 128;
    const int xo0 = ((c0 ^ fsw(row0)) & 3) * 8;
    const int xo1 = ((c0 ^ fsw(row1)) & 3) * 8;

    const u16* gA0 = h_in + (size_t)(m0 + row0) * HH + xo0;
    const u16* gA1 = h_in + (size_t)(m0 + row1) * HH + xo1;
    const u16* gB0 = wperm + (R0 + row0) * HH + xo0;
    const u16* gB1 = wperm + (R0 + row1) * HH + xo1;

    // fragment read offsets (swizzled)
    int aoff[8], boff[4];
#pragma unroll
    for (int mf = 0; mf < 8; ++mf) {
        int r = qr * 128 + mf * 16 + r16;
        aoff[mf] = r * 32 + ((s4 ^ fsw(r)) & 3) * 8;
    }
#pragma unroll
    for (int nf = 0; nf < 4; ++nf) {
        int r = qn * 64 + nf * 16 + r16;
        boff[nf] = r * 32 + ((s4 ^ fsw(r)) & 3) * 8;
    }

    // acc init with bias
    f32x4 acc[8][4];
    const int n = nt * 64 + qn * 16 + r16;
    if (!tail) {
#pragma unroll
        for (int nf = 0; nf < 4; ++nf) {
            float bv = bias[nf * HH + n];
#pragma unroll
            for (int mf = 0; mf < 8; ++mf) acc[mf][nf] = (f32x4){bv, bv, bv, bv};
        }
    }
    f32x4 pacc[8];
    const int p = qn * 16 + r16;
    if (my_proj) {
        float pv = (p < INP) ? blin[p] : 0.f;
#pragma unroll
        for (int mf = 0; mf < 8; ++mf) pacc[mf] = (f32x4){pv, pv, pv, pv};
    }
    const u16* gP = wperm + (size_t)(4096 + p) * HH + s4 * 8;

    // ---- prologue: stage x-tile (K padded 17->32) into buf 0 ----
    cp16(&sA[0][tid * 8],         xpad + ((size_t)t * BB + m0 + row0) * 32 + xo0);
    cp16(&sA[0][(tid + 512) * 8], xpad + ((size_t)t * BB + m0 + row1) * 32 + xo1);
    if (!tail) {
        cp16(&sB[0][tid * 8],         wxperm + (R0 + row0) * 32 + xo0);
        cp16(&sB[0][(tid + 512) * 8], wxperm + (R0 + row1) * 32 + xo1);
    }
    __syncthreads();

    // ---- 2-phase pipeline over 33 K-tiles ----
    for (int kt = 0; kt < 33; ++kt) {
        const int cb = kt & 1, nb = cb ^ 1;
        if (kt < 32) {                      // stage tile kt+1 (h K-offset kt*32)
            const int ko = kt * 32;
            cp16(&sA[nb][tid * 8],         gA0 + ko);
            cp16(&sA[nb][(tid + 512) * 8], gA1 + ko);
            if (!tail) {
                cp16(&sB[nb][tid * 8],         gB0 + ko);
                cp16(&sB[nb][(tid + 512) * 8], gB1 + ko);
            }
        }
        bf16x8 b[4];
        if (!tail) {
#pragma unroll
            for (int nf = 0; nf < 4; ++nf)
                b[nf] = __builtin_bit_cast(bf16x8, *(const short8*)&sB[cb][boff[nf]]);
        }
        bf16x8 pb;
        const bool do_p = my_proj && (kt > 0);
        if (do_p) pb = ld16(gP + (kt - 1) * 32);
#pragma unroll
        for (int h2 = 0; h2 < 2; ++h2) {
            bf16x8 a[4];
#pragma unroll
            for (int i = 0; i < 4; ++i)
                a[i] = __builtin_bit_cast(bf16x8, *(const short8*)&sA[cb][aoff[h2 * 4 + i]]);
            if (!tail) {
#pragma unroll
                for (int nf = 0; nf < 4; ++nf)
#pragma unroll
                    for (int i = 0; i < 4; ++i)
                        acc[h2 * 4 + i][nf] = __builtin_amdgcn_mfma_f32_16x16x32_bf16(
                            a[i], b[nf], acc[h2 * 4 + i][nf], 0, 0, 0);
            }
            if (do_p) {
#pragma unroll
                for (int i = 0; i < 4; ++i)
                    pacc[h2 * 4 + i] = __builtin_amdgcn_mfma_f32_16x16x32_bf16(
                        a[i], pb, pacc[h2 * 4 + i], 0, 0, 0);
            }
        }
        __syncthreads();
    }

    // ---- epilogue: LSTM cell ----
    if (!tail) {
#pragma unroll
        for (int mf = 0; mf < 8; ++mf)
#pragma unroll
            for (int j = 0; j < 4; ++j) {
                int row = m0 + qr * 128 + mf * 16 + s4 * 4 + j;
                float iv = fast_sigmoid(acc[mf][0][j]);
                float fv = fast_sigmoid(acc[mf][1][j]);
                float gv = fast_tanh(acc[mf][2][j]);
                float ov = fast_sigmoid(acc[mf][3][j]);
                size_t ci = (size_t)row * HH + n;
                float cold = __builtin_nontemporal_load(&c_buf[ci]);
                float cnew = fv * cold + iv * gv;
                float hnew = ov * fast_tanh(cnew);
                __builtin_nontemporal_store(cnew, &c_buf[ci]);
                h_out[ci] = f2bfu(hnew);
                if (is_last) __builtin_nontemporal_store(hnew, &h_fin[ci]);
            }
    }
    // ---- proj store: out_{t-1} ----
    if (my_proj && t > 0 && p < INP) {
#pragma unroll
        for (int mf = 0; mf < 8; ++mf)
#pragma unroll
            for (int j = 0; j < 4; ++j) {
                int row = m0 + qr * 128 + mf * 16 + s4 * 4 + j;
                __builtin_nontemporal_store(
                    pacc[mf][j], &outp[((size_t)row * TT + (t - 1)) * INP + p]);
            }
    }
}

// ---------------- launch ----------------
extern "C" void kernel_launch(void* const* d_in, const int* in_sizes, int n_in,
                              void* d_out, int out_size, void* d_ws, size_t ws_size,
                              hipStream_t stream)
{
    const float* x    = (const float*)d_in[0];
    const float* Wih  = (const float*)d_in[1];
    const float* Whh  = (const float*)d_in[2];
    const float* bih  = (const float*)d_in[3];
    const float* bhh  = (const float*)d_in[4];
    const float* Wlin = (const float*)d_in[5];
    const float* blin = (const float*)d_in[6];
    float* out = (float*)d_out;

    char* ws = (char*)d_ws;
    u16* hb0     = (u16*)(ws);                     //  8,388,608 B
    u16* hb1     = (u16*)(ws +  8388608);          //  8,388,608 B
    u16* xpad    = (u16*)(ws + 16777216);          //  5,242,880 B (20 t-slots)
    u16* wperm   = (u16*)(ws + 22020096);          //  8,454,144 B (4128 x 1024)
    u16* wxperm  = (u16*)(ws + 30474240);          //    264,192 B (4128 x 32)
    float* bias  = (float*)(ws + 30738432);        //     16,384 B

    float* h_fin = out + (size_t)BB * TT * INP;    // h_fin region
    float* c_buf = h_fin + (size_t)BB * HH;        // c_fin region = c state

    hipMemsetAsync(hb0, 0, (size_t)BB * HH * sizeof(u16), stream);
    hipMemsetAsync(c_buf, 0, (size_t)BB * HH * sizeof(float), stream);
    hipMemsetAsync((char*)xpad + (size_t)19 * BB * 32 * 2, 0, BB * 32 * 2, stream);

    prep_wperm<<<2064, 256, 0, stream>>>(Whh, Wlin, wperm);
    prep_wx<<<516, 256, 0, stream>>>(Wih, wxperm);
    prep_bias<<<16, 256, 0, stream>>>(bih, bhh, bias);
    prep_x<<<9728, 256, 0, stream>>>(x, xpad);

    for (int t = 0; t < TT; ++t) {
        const u16* hin = (t & 1) ? hb1 : hb0;
        u16* hout = (t & 1) ? hb0 : hb1;
        lstm_step<<<256, 512, 0, stream>>>(
            hin, hout, c_buf, wperm, wxperm, bias, xpad, blin, out,
            h_fin, t, (t == TT - 1) ? 1 : 0, 0);
    }
    // tail: out_18 = h_19 @ W_lin^T + b_lin  (h_19 is in hb1 after t=18)
    lstm_step<<<16, 512, 0, stream>>>(
        hb1, hb0, c_buf, wperm, wxperm, bias, xpad, blin, out,
        h_fin, TT, 0, 1);
}

// Round 11
// 1165.236 us; speedup vs baseline: 1.2393x; 1.1486x over previous
//
#include <hip/hip_runtime.h>
#include <hip/hip_bf16.h>

typedef unsigned short u16;
typedef __attribute__((ext_vector_type(8))) __bf16 bf16x8;
typedef __attribute__((ext_vector_type(8))) short short8;
typedef __attribute__((ext_vector_type(4))) float f32x4;

#define BB 4096
#define TT 19
#define INP 17
#define HH 1024
#define NE 4128          // 4096 permuted gate entries + 32 proj rows
#define NT_PROJ 15       // proj rows are staged/used by nt==15 blocks

// dynamic LDS map (u16 units): A dbuf 2x16384, B dbuf 2x16384, P dbuf 2x2048
#define ABASE(b) ((b) * 16384)
#define BBASE(b) (32768 + (b) * 16384)
#define PBASE(b) (65536 + (b) * 2048)
#define LDS_BYTES 139264

#define FENCE asm volatile("" ::: "memory")

__device__ __forceinline__ u16 f2bfu(float f) {
    __hip_bfloat16 b = __float2bfloat16(f);
    return __builtin_bit_cast(unsigned short, b);
}
__device__ __forceinline__ float fast_sigmoid(float x) {
    return 1.f / (1.f + __expf(-x));
}
__device__ __forceinline__ float fast_tanh(float x) {
    float e = __expf(2.f * x);
    return (e - 1.f) / (e + 1.f);
}
__device__ __forceinline__ bf16x8 ldfrag(const u16* p) {
    return __builtin_bit_cast(bf16x8, *(const short8*)p);
}
// async 16B global -> LDS (linear dest = wave base + lane*16)
__device__ __forceinline__ void cp16(const u16* l, const void* g) {
    __builtin_amdgcn_global_load_lds(
        (const __attribute__((address_space(1))) unsigned int*)g,
        (__attribute__((address_space(3))) unsigned int*)l, 16, 0, 0);
}

// ---------------- prep kernels ----------------
// wperm[NE][HH]: entry r of tile nt -> gate (r>>4)&3, hcol nt*64+(r>>6)*16+(r&15);
// rows 4096..4127 = W_lin rows (17 real + zero pad). grid MUST be 2064.
__global__ void prep_wperm(const float* __restrict__ Whh, const float* __restrict__ Wlin,
                           u16* __restrict__ wperm) {
    size_t idx = ((size_t)blockIdx.x * 256 + threadIdx.x) * 8;
    int R = (int)(idx >> 10);
    int k = (int)(idx & 1023);
    const float* src = nullptr;
    if (R < 4096) {
        int nt = R >> 8, r = R & 255;
        int qn = r >> 6, nf = (r >> 4) & 3, cj = r & 15;
        int hcol = nt * 64 + qn * 16 + cj;
        src = Whh + ((size_t)(nf * HH + hcol)) * HH + k;
    } else if (R - 4096 < INP) {
        src = Wlin + (size_t)(R - 4096) * HH + k;
    }
#pragma unroll
    for (int e = 0; e < 8; ++e) wperm[idx + e] = src ? f2bfu(src[e]) : (u16)0;
}

// wx64[NE][64]: same row permutation of W_ih, K padded 17->64. grid 1032.
__global__ void prep_wx64(const float* __restrict__ Wih, u16* __restrict__ wx64) {
    int idx = blockIdx.x * 256 + threadIdx.x;
    int R = idx >> 6, k = idx & 63;
    u16 v = 0;
    if (R < 4096 && k < INP) {
        int nt = R >> 8, r = R & 255;
        int qn = r >> 6, nf = (r >> 4) & 3, cj = r & 15;
        int hcol = nt * 64 + qn * 16 + cj;
        v = f2bfu(Wih[(size_t)(nf * HH + hcol) * INP + k]);
    }
    wx64[idx] = v;
}

// bias[4096] = b_ih + b_hh. grid 16.
__global__ void prep_bias(const float* __restrict__ bih, const float* __restrict__ bhh,
                          float* __restrict__ bias) {
    int idx = blockIdx.x * 256 + threadIdx.x;
    bias[idx] = bih[idx] + bhh[idx];
}

// xpad64[t][b][64], K padded 17->64. grid 19456 (covers t<19; slot 19 memset).
__global__ void prep_x64(const float* __restrict__ x, u16* __restrict__ xpad) {
    int idx = blockIdx.x * 256 + threadIdx.x;
    int c = idx & 63;
    int rb = idx >> 6;
    int t = rb >> 12;
    int b = rb & 4095;
    xpad[idx] = (c < INP) ? f2bfu(x[((size_t)b * TT + t) * INP + c]) : (u16)0;
}

// ------- fused step kernel: 256x256, BK=64, counted-vmcnt pipeline -------
// grid 256 = 16 mt x 16 nt (XCD 2D-chunked), 512 threads = 8 waves (2qr x 4qn).
// 17 K-tiles (tile 0 = x/wx64 K=64-padded; tiles 1..16 = h/wperm). Double-
// buffered LDS; per tile: issue next tile's 8(+1) global_load_lds, then
// s_waitcnt vmcnt(9/8) (previous tile resident, NEW loads stay in flight),
// raw s_barrier, MFMA from current buffer, raw s_barrier. Never vmcnt(0)
// in the steady loop (T4). nt==15: waves qn<2 also accumulate the output
// projection from the sP panel (W_lin rows staged in the same load stream).
__global__ __launch_bounds__(512, 2) void lstm_step(
    const u16* __restrict__ h_in, u16* __restrict__ h_out,
    float* __restrict__ c_buf, const u16* __restrict__ wperm,
    const u16* __restrict__ wx64, const float* __restrict__ bias,
    const u16* __restrict__ xpad64, const float* __restrict__ blin,
    float* __restrict__ outp, float* __restrict__ h_fin,
    int t, int is_last, int tail)
{
    extern __shared__ u16 lds[];

    const int tid = threadIdx.x;
    const int lane = tid & 63;
    const int wv = tid >> 6;
    const int qr = wv >> 2, qn = wv & 3;
    const int r16 = lane & 15, s4 = lane >> 4;

    int mt, nt;
    if (tail) { mt = blockIdx.x; nt = NT_PROJ; }
    else {
        const int xcd = blockIdx.x & 7, local = blockIdx.x >> 3;
        mt = (xcd >> 2) * 8 + (local & 7);
        nt = (xcd & 3) * 4 + (local >> 3);
    }
    const int m0 = mt * 256;
    const size_t R0 = (size_t)nt * 256;
    const bool my_proj = (nt == NT_PROJ) && (qn < 2);

    // staging: 4 dest slots per thread (A and B each); slot d -> row d>>3,
    // physical 16B chunk d&7 holds logical chunk gc = (d&7)^(row&7) (XOR
    // involution; read side applies the same XOR -> conflict-free b128 reads).
    int srow[4], sgc[4];
#pragma unroll
    for (int i = 0; i < 4; ++i) {
        int d = tid + i * 512;
        srow[i] = d >> 3;
        sgc[i] = (d & 7) ^ (srow[i] & 7);
    }
    const u16* hA[4];
    const u16* wB[4];
#pragma unroll
    for (int i = 0; i < 4; ++i) {
        hA[i] = h_in + (size_t)(m0 + srow[i]) * HH + sgc[i] * 8;
        wB[i] = wperm + (R0 + srow[i]) * HH + sgc[i] * 8;
    }
    const int prow = (tid >> 3) & 31;
    const int pgc = (tid & 7) ^ (prow & 7);
    const u16* wP = wperm + (size_t)(4096 + prow) * HH + pgc * 8;

    // fragment offsets for kk=0; kk=1 is ^32 (slot^4 -> byte^64 -> elem^32)
    int aoff[8], boff[4], poff;
#pragma unroll
    for (int mf = 0; mf < 8; ++mf) {
        int r = qr * 128 + mf * 16 + r16;
        aoff[mf] = r * 64 + ((s4 ^ (r & 7)) * 8);
    }
#pragma unroll
    for (int nf = 0; nf < 4; ++nf) {
        int r = qn * 64 + nf * 16 + r16;
        boff[nf] = r * 64 + ((s4 ^ (r & 7)) * 8);
    }
    {
        int r = qn * 16 + r16;           // 0..31 for proj waves
        poff = r * 64 + ((s4 ^ (r & 7)) * 8);
    }

    // acc init with bias
    f32x4 acc[8][4];
    const int n = nt * 64 + qn * 16 + r16;
    if (!tail) {
#pragma unroll
        for (int nf = 0; nf < 4; ++nf) {
            float bv = bias[nf * HH + n];
#pragma unroll
            for (int mf = 0; mf < 8; ++mf) acc[mf][nf] = (f32x4){bv, bv, bv, bv};
        }
    }
    f32x4 pacc[8];
    const int p = qn * 16 + r16;
    if (my_proj) {
        float pv = (p < INP) ? blin[p] : 0.f;
#pragma unroll
        for (int mf = 0; mf < 8; ++mf) pacc[mf] = (f32x4){pv, pv, pv, pv};
    }

    // ---- prologue: stage tile 0 (x | wx64; P slot = placeholder) ----
    const u16* xA = xpad64 + ((size_t)t * BB + m0) * 64;
#pragma unroll
    for (int i = 0; i < 4; ++i)
        cp16(&lds[ABASE(0) + (tid + i * 512) * 8], xA + (size_t)srow[i] * 64 + sgc[i] * 8);
#pragma unroll
    for (int i = 0; i < 4; ++i)
        cp16(&lds[BBASE(0) + (tid + i * 512) * 8], wx64 + (R0 + srow[i]) * 64 + sgc[i] * 8);
    if (wv < 4) cp16(&lds[PBASE(0) + tid * 8], wP);

    // ---- pipeline over 17 K-tiles ----
    for (int j = 0; j < 17; ++j) {
        const int cb = j & 1, nb = cb ^ 1;
        if (j < 16) {
            const int ko = j * 64;        // h K-offset of tile j+1
#pragma unroll
            for (int i = 0; i < 4; ++i)
                cp16(&lds[ABASE(nb) + (tid + i * 512) * 8], hA[i] + ko);
#pragma unroll
            for (int i = 0; i < 4; ++i)
                cp16(&lds[BBASE(nb) + (tid + i * 512) * 8], wB[i] + ko);
            if (wv < 4) {
                cp16(&lds[PBASE(nb) + tid * 8], wP + ko);
                asm volatile("s_waitcnt vmcnt(9)" ::: "memory");
            } else {
                asm volatile("s_waitcnt vmcnt(8)" ::: "memory");
            }
        } else {
            asm volatile("s_waitcnt vmcnt(0)" ::: "memory");
        }
        __builtin_amdgcn_s_barrier();
        FENCE;

        const int cbA = ABASE(cb), cbB = BBASE(cb), cbP = PBASE(cb);
        const bool do_p = my_proj && (j > 0);
#pragma unroll
        for (int kk = 0; kk < 2; ++kk) {
            const int kx = kk * 32;
            bf16x8 b[4];
            if (!tail) {
#pragma unroll
                for (int nf = 0; nf < 4; ++nf)
                    b[nf] = ldfrag(&lds[cbB + (boff[nf] ^ kx)]);
            }
            bf16x8 pb;
            if (do_p) pb = ldfrag(&lds[cbP + (poff ^ kx)]);
#pragma unroll
            for (int h2 = 0; h2 < 2; ++h2) {
                bf16x8 a[4];
#pragma unroll
                for (int i = 0; i < 4; ++i)
                    a[i] = ldfrag(&lds[cbA + (aoff[h2 * 4 + i] ^ kx)]);
                if (!tail) {
#pragma unroll
                    for (int nf = 0; nf < 4; ++nf)
#pragma unroll
                        for (int i = 0; i < 4; ++i)
                            acc[h2 * 4 + i][nf] = __builtin_amdgcn_mfma_f32_16x16x32_bf16(
                                a[i], b[nf], acc[h2 * 4 + i][nf], 0, 0, 0);
                }
                if (do_p) {
#pragma unroll
                    for (int i = 0; i < 4; ++i)
                        pacc[h2 * 4 + i] = __builtin_amdgcn_mfma_f32_16x16x32_bf16(
                            a[i], pb, pacc[h2 * 4 + i], 0, 0, 0);
                }
            }
        }
        FENCE;
        __builtin_amdgcn_s_barrier();
        FENCE;
    }

    // ---- epilogue: LSTM cell (r10-verified) ----
    if (!tail) {
#pragma unroll
        for (int mf = 0; mf < 8; ++mf)
#pragma unroll
            for (int j = 0; j < 4; ++j) {
                int row = m0 + qr * 128 + mf * 16 + s4 * 4 + j;
                float iv = fast_sigmoid(acc[mf][0][j]);
                float fv = fast_sigmoid(acc[mf][1][j]);
                float gv = fast_tanh(acc[mf][2][j]);
                float ov = fast_sigmoid(acc[mf][3][j]);
                size_t ci = (size_t)row * HH + n;
                float cold = __builtin_nontemporal_load(&c_buf[ci]);
                float cnew = fv * cold + iv * gv;
                float hnew = ov * fast_tanh(cnew);
                __builtin_nontemporal_store(cnew, &c_buf[ci]);
                h_out[ci] = f2bfu(hnew);
                if (is_last) __builtin_nontemporal_store(hnew, &h_fin[ci]);
            }
    }
    // ---- proj store: out_{t-1} ----
    if (my_proj && t > 0 && p < INP) {
#pragma unroll
        for (int mf = 0; mf < 8; ++mf)
#pragma unroll
            for (int j = 0; j < 4; ++j) {
                int row = m0 + qr * 128 + mf * 16 + s4 * 4 + j;
                __builtin_nontemporal_store(
                    pacc[mf][j], &outp[((size_t)row * TT + (t - 1)) * INP + p]);
            }
    }
}

// ---------------- launch ----------------
extern "C" void kernel_launch(void* const* d_in, const int* in_sizes, int n_in,
                              void* d_out, int out_size, void* d_ws, size_t ws_size,
                              hipStream_t stream)
{
    const float* x    = (const float*)d_in[0];
    const float* Wih  = (const float*)d_in[1];
    const float* Whh  = (const float*)d_in[2];
    const float* bih  = (const float*)d_in[3];
    const float* bhh  = (const float*)d_in[4];
    const float* Wlin = (const float*)d_in[5];
    const float* blin = (const float*)d_in[6];
    float* out = (float*)d_out;

    char* ws = (char*)d_ws;
    u16* hb0     = (u16*)(ws);                     //  8,388,608 B
    u16* hb1     = (u16*)(ws +  8388608);          //  8,388,608 B
    u16* xpad64  = (u16*)(ws + 16777216);          // 10,485,760 B (20 t-slots x 64)
    u16* wperm   = (u16*)(ws + 27262976);          //  8,454,144 B (4128 x 1024)
    u16* wx64    = (u16*)(ws + 35717120);          //    528,384 B (4128 x 64)
    float* bias  = (float*)(ws + 36245504);        //     16,384 B

    float* h_fin = out + (size_t)BB * TT * INP;    // h_fin region
    float* c_buf = h_fin + (size_t)BB * HH;        // c_fin region = c state

    hipFuncSetAttribute((const void*)lstm_step,
                        hipFuncAttributeMaxDynamicSharedMemorySize, LDS_BYTES);

    hipMemsetAsync(hb0, 0, (size_t)BB * HH * sizeof(u16), stream);
    hipMemsetAsync(c_buf, 0, (size_t)BB * HH * sizeof(float), stream);
    hipMemsetAsync((char*)xpad64 + (size_t)19 * BB * 64 * 2, 0, BB * 64 * 2, stream);

    prep_wperm<<<2064, 256, 0, stream>>>(Whh, Wlin, wperm);
    prep_wx64<<<1032, 256, 0, stream>>>(Wih, wx64);
    prep_bias<<<16, 256, 0, stream>>>(bih, bhh, bias);
    prep_x64<<<19456, 256, 0, stream>>>(x, xpad64);

    for (int t = 0; t < TT; ++t) {
        const u16* hin = (t & 1) ? hb1 : hb0;
        u16* hout = (t & 1) ? hb0 : hb1;
        lstm_step<<<256, 512, LDS_BYTES, stream>>>(
            hin, hout, c_buf, wperm, wx64, bias, xpad64, blin, out,
            h_fin, t, (t == TT - 1) ? 1 : 0, 0);
    }
    // tail: out_18 = h_19 @ W_lin^T + b_lin  (h_19 is in hb1 after t=18)
    lstm_step<<<16, 512, LDS_BYTES, stream>>>(
        hb1, hb0, c_buf, wperm, wx64, bias, xpad64, blin, out,
        h_fin, TT, 0, 1);
}

// Round 12
// 1026.927 us; speedup vs baseline: 1.4062x; 1.1347x over previous
//
#include <hip/hip_runtime.h>
#include <hip/hip_bf16.h>

typedef unsigned short u16;
typedef __attribute__((ext_vector_type(8))) __bf16 bf16x8;
typedef __attribute__((ext_vector_type(8))) short short8;
typedef __attribute__((ext_vector_type(4))) float f32x4;

#define BB 4096
#define TT 19
#define INP 17
#define HH 1024
#define NE 4128          // 4096 permuted gate entries + 32 proj rows
#define NT_PROJ 15       // proj rows are staged/used by nt==15 blocks

// dynamic LDS map (u16 units): A dbuf 2x16384, B dbuf 2x16384, P dbuf 2x2048
// epilogue reuse: h tile [256][64] u16 -> A0 region; c tile [256][64] f32 ->
// A1 (rows 0..127) + B1 (rows 128..255) regions.
#define ABASE(b) ((b) * 16384)
#define BBASE(b) (32768 + (b) * 16384)
#define PBASE(b) (65536 + (b) * 2048)
#define LDS_BYTES 139264

#define FENCE asm volatile("" ::: "memory")

__device__ __forceinline__ u16 f2bfu(float f) {
    __hip_bfloat16 b = __float2bfloat16(f);
    return __builtin_bit_cast(unsigned short, b);
}
__device__ __forceinline__ float fast_sigmoid(float x) {
    return 1.f / (1.f + __expf(-x));
}
__device__ __forceinline__ float fast_tanh(float x) {
    float e = __expf(2.f * x);
    return (e - 1.f) / (e + 1.f);
}
__device__ __forceinline__ bf16x8 ldfrag(const u16* p) {
    return __builtin_bit_cast(bf16x8, *(const short8*)p);
}
// c-tile row base in u16 units (A1 for rows 0..127, B1 for 128..255)
__device__ __forceinline__ int cBase(int row) {
    return row < 128 ? 16384 + row * 128 : 49152 + (row - 128) * 128;
}
// async 16B global -> LDS (linear dest = wave base + lane*16)
__device__ __forceinline__ void cp16(const u16* l, const void* g) {
    __builtin_amdgcn_global_load_lds(
        (const __attribute__((address_space(1))) unsigned int*)g,
        (__attribute__((address_space(3))) unsigned int*)l, 16, 0, 0);
}

// ---------------- prep kernels ----------------
// wperm[NE][HH]: entry r of tile nt -> gate (r>>4)&3, hcol nt*64+(r>>6)*16+(r&15);
// rows 4096..4127 = W_lin rows (17 real + zero pad). grid MUST be 2064.
__global__ void prep_wperm(const float* __restrict__ Whh, const float* __restrict__ Wlin,
                           u16* __restrict__ wperm) {
    size_t idx = ((size_t)blockIdx.x * 256 + threadIdx.x) * 8;
    int R = (int)(idx >> 10);
    int k = (int)(idx & 1023);
    const float* src = nullptr;
    if (R < 4096) {
        int nt = R >> 8, r = R & 255;
        int qn = r >> 6, nf = (r >> 4) & 3, cj = r & 15;
        int hcol = nt * 64 + qn * 16 + cj;
        src = Whh + ((size_t)(nf * HH + hcol)) * HH + k;
    } else if (R - 4096 < INP) {
        src = Wlin + (size_t)(R - 4096) * HH + k;
    }
#pragma unroll
    for (int e = 0; e < 8; ++e) wperm[idx + e] = src ? f2bfu(src[e]) : (u16)0;
}

// wx64[NE][64]: same row permutation of W_ih, K padded 17->64. grid 1032.
__global__ void prep_wx64(const float* __restrict__ Wih, u16* __restrict__ wx64) {
    int idx = blockIdx.x * 256 + threadIdx.x;
    int R = idx >> 6, k = idx & 63;
    u16 v = 0;
    if (R < 4096 && k < INP) {
        int nt = R >> 8, r = R & 255;
        int qn = r >> 6, nf = (r >> 4) & 3, cj = r & 15;
        int hcol = nt * 64 + qn * 16 + cj;
        v = f2bfu(Wih[(size_t)(nf * HH + hcol) * INP + k]);
    }
    wx64[idx] = v;
}

// bias[4096] = b_ih + b_hh. grid 16.
__global__ void prep_bias(const float* __restrict__ bih, const float* __restrict__ bhh,
                          float* __restrict__ bias) {
    int idx = blockIdx.x * 256 + threadIdx.x;
    bias[idx] = bih[idx] + bhh[idx];
}

// xpad64[t][b][64], K padded 17->64. grid 19456 (covers t<19; slot 19 memset).
__global__ void prep_x64(const float* __restrict__ x, u16* __restrict__ xpad) {
    int idx = blockIdx.x * 256 + threadIdx.x;
    int c = idx & 63;
    int rb = idx >> 6;
    int t = rb >> 12;
    int b = rb & 4095;
    xpad[idx] = (c < INP) ? f2bfu(x[((size_t)b * TT + t) * INP + c]) : (u16)0;
}

// ------- fused step kernel: 256x256, BK=64, counted-vmcnt pipeline -------
// grid 256 = 16 mt x 16 nt (XCD 2D-chunked), 512 threads = 8 waves (2qr x 4qn).
// 17 K-tiles (tile 0 = x/wx64; 1..16 = h/wperm), double-buffered, counted
// vmcnt (never 0 in steady loop). Last tile also stages c_old into the free
// LDS halves (overlapped). Epilogue: cell in regs -> h/c tiles in LDS ->
// fully-coalesced row-major stores (256B c rows, 128B h rows).
__global__ __launch_bounds__(512, 2) void lstm_step(
    const u16* __restrict__ h_in, u16* __restrict__ h_out,
    float* __restrict__ c_buf, const u16* __restrict__ wperm,
    const u16* __restrict__ wx64, const float* __restrict__ bias,
    const u16* __restrict__ xpad64, const float* __restrict__ blin,
    float* __restrict__ outp, float* __restrict__ h_fin,
    int t, int is_last, int tail)
{
    extern __shared__ u16 lds[];

    const int tid = threadIdx.x;
    const int lane = tid & 63;
    const int wv = tid >> 6;
    const int qr = wv >> 2, qn = wv & 3;
    const int r16 = lane & 15, s4 = lane >> 4;

    int mt, nt;
    if (tail) { mt = blockIdx.x; nt = NT_PROJ; }
    else {
        const int xcd = blockIdx.x & 7, local = blockIdx.x >> 3;
        mt = (xcd >> 2) * 8 + (local & 7);
        nt = (xcd & 3) * 4 + (local >> 3);
    }
    const int m0 = mt * 256;
    const size_t R0 = (size_t)nt * 256;
    const bool my_proj = (nt == NT_PROJ) && (qn < 2);

    // staging: 4 dest slots per thread (A and B each); slot d -> row d>>3,
    // physical 16B chunk d&7 holds logical chunk gc = (d&7)^(row&7).
    int srow[4], sgc[4];
#pragma unroll
    for (int i = 0; i < 4; ++i) {
        int d = tid + i * 512;
        srow[i] = d >> 3;
        sgc[i] = (d & 7) ^ (srow[i] & 7);
    }
    const u16* hA[4];
    const u16* wB[4];
#pragma unroll
    for (int i = 0; i < 4; ++i) {
        hA[i] = h_in + (size_t)(m0 + srow[i]) * HH + sgc[i] * 8;
        wB[i] = wperm + (R0 + srow[i]) * HH + sgc[i] * 8;
    }
    const int prow = (tid >> 3) & 31;
    const int pgc = (tid & 7) ^ (prow & 7);
    const u16* wP = wperm + (size_t)(4096 + prow) * HH + pgc * 8;

    // fragment offsets for kk=0; kk=1 is ^32
    int aoff[8], boff[4], poff;
#pragma unroll
    for (int mf = 0; mf < 8; ++mf) {
        int r = qr * 128 + mf * 16 + r16;
        aoff[mf] = r * 64 + ((s4 ^ (r & 7)) * 8);
    }
#pragma unroll
    for (int nf = 0; nf < 4; ++nf) {
        int r = qn * 64 + nf * 16 + r16;
        boff[nf] = r * 64 + ((s4 ^ (r & 7)) * 8);
    }
    {
        int r = qn * 16 + r16;
        poff = r * 64 + ((s4 ^ (r & 7)) * 8);
    }

    // acc init with bias
    f32x4 acc[8][4];
    const int n = nt * 64 + qn * 16 + r16;
    if (!tail) {
#pragma unroll
        for (int nf = 0; nf < 4; ++nf) {
            float bv = bias[nf * HH + n];
#pragma unroll
            for (int mf = 0; mf < 8; ++mf) acc[mf][nf] = (f32x4){bv, bv, bv, bv};
        }
    }
    f32x4 pacc[8];
    const int p = qn * 16 + r16;
    if (my_proj) {
        float pv = (p < INP) ? blin[p] : 0.f;
#pragma unroll
        for (int mf = 0; mf < 8; ++mf) pacc[mf] = (f32x4){pv, pv, pv, pv};
    }

    // ---- prologue: stage tile 0 (x | wx64 | P) ----
    const u16* xA = xpad64 + ((size_t)t * BB + m0) * 64;
#pragma unroll
    for (int i = 0; i < 4; ++i)
        cp16(&lds[ABASE(0) + (tid + i * 512) * 8], xA + (size_t)srow[i] * 64 + sgc[i] * 8);
#pragma unroll
    for (int i = 0; i < 4; ++i)
        cp16(&lds[BBASE(0) + (tid + i * 512) * 8], wx64 + (R0 + srow[i]) * 64 + sgc[i] * 8);
    if (wv < 4) cp16(&lds[PBASE(0) + tid * 8], wP);

    // ---- pipeline over 17 K-tiles ----
    for (int j = 0; j < 17; ++j) {
        const int cb = j & 1, nb = cb ^ 1;
        if (j < 16) {
            const int ko = j * 64;        // h K-offset of tile j+1
#pragma unroll
            for (int i = 0; i < 4; ++i)
                cp16(&lds[ABASE(nb) + (tid + i * 512) * 8], hA[i] + ko);
#pragma unroll
            for (int i = 0; i < 4; ++i)
                cp16(&lds[BBASE(nb) + (tid + i * 512) * 8], wB[i] + ko);
            if (wv < 4) {
                cp16(&lds[PBASE(nb) + tid * 8], wP + ko);
                asm volatile("s_waitcnt vmcnt(9)" ::: "memory");
            } else {
                asm volatile("s_waitcnt vmcnt(8)" ::: "memory");
            }
        } else if (!tail) {
            // stage c_old tile (256x64 f32) into A1+B1 regions, coalesced:
            // slot s = tid + i*512; row = s>>4, 16B chunk = s&15.
#pragma unroll
            for (int i = 0; i < 8; ++i) {
                const int s = tid + i * 512;
                const int crow = s >> 4, cch = s & 15;
                const u16* dst = (i < 4) ? &lds[16384 + s * 8] : &lds[32768 + s * 8];
                cp16(dst, c_buf + (size_t)(m0 + crow) * HH + nt * 64 + cch * 4);
            }
            asm volatile("s_waitcnt vmcnt(8)" ::: "memory");
        } else {
            asm volatile("s_waitcnt vmcnt(0)" ::: "memory");
        }
        __builtin_amdgcn_s_barrier();
        FENCE;

        const int cbA = ABASE(cb), cbB = BBASE(cb), cbP = PBASE(cb);
        const bool do_p = my_proj && (j > 0);
        __builtin_amdgcn_s_setprio(1);
#pragma unroll
        for (int kk = 0; kk < 2; ++kk) {
            const int kx = kk * 32;
            bf16x8 b[4];
            if (!tail) {
#pragma unroll
                for (int nf = 0; nf < 4; ++nf)
                    b[nf] = ldfrag(&lds[cbB + (boff[nf] ^ kx)]);
            }
            bf16x8 pb;
            if (do_p) pb = ldfrag(&lds[cbP + (poff ^ kx)]);
#pragma unroll
            for (int h2 = 0; h2 < 2; ++h2) {
                bf16x8 a[4];
#pragma unroll
                for (int i = 0; i < 4; ++i)
                    a[i] = ldfrag(&lds[cbA + (aoff[h2 * 4 + i] ^ kx)]);
                if (!tail) {
#pragma unroll
                    for (int nf = 0; nf < 4; ++nf)
#pragma unroll
                        for (int i = 0; i < 4; ++i)
                            acc[h2 * 4 + i][nf] = __builtin_amdgcn_mfma_f32_16x16x32_bf16(
                                a[i], b[nf], acc[h2 * 4 + i][nf], 0, 0, 0);
                }
                if (do_p) {
#pragma unroll
                    for (int i = 0; i < 4; ++i)
                        pacc[h2 * 4 + i] = __builtin_amdgcn_mfma_f32_16x16x32_bf16(
                            a[i], pb, pacc[h2 * 4 + i], 0, 0, 0);
                }
            }
        }
        __builtin_amdgcn_s_setprio(0);
        FENCE;
        __builtin_amdgcn_s_barrier();
        FENCE;
    }

    // ---- epilogue: cell in regs -> LDS tiles -> coalesced stores ----
    if (!tail) {
        asm volatile("s_waitcnt vmcnt(0)" ::: "memory");
        __syncthreads();                  // c_old tile resident for all
        const int cl = qn * 16 + r16;     // col 0..63 within tile
#pragma unroll
        for (int mf = 0; mf < 8; ++mf)
#pragma unroll
            for (int j = 0; j < 4; ++j) {
                int rl = qr * 128 + mf * 16 + s4 * 4 + j;
                float iv = fast_sigmoid(acc[mf][0][j]);
                float fv = fast_sigmoid(acc[mf][1][j]);
                float gv = fast_tanh(acc[mf][2][j]);
                float ov = fast_sigmoid(acc[mf][3][j]);
                float* crow = (float*)&lds[cBase(rl)];
                float cold = crow[cl];
                float cnew = fv * cold + iv * gv;
                float hnew = ov * fast_tanh(cnew);
                crow[cl] = cnew;                       // c tile in-place
                lds[rl * 64 + cl] = f2bfu(hnew);       // h tile (A0 region)
                if (is_last)
                    __builtin_nontemporal_store(
                        hnew, &h_fin[(size_t)(m0 + rl) * HH + n]);
            }
        __syncthreads();
        // coalesced stores: wave wv owns rows wv*32..wv*32+31; lane = col.
#pragma unroll 4
        for (int r = 0; r < 32; ++r) {
            const int rl = wv * 32 + r;
            const size_t gi = (size_t)(m0 + rl) * HH + nt * 64 + lane;
            __builtin_nontemporal_store(((float*)&lds[cBase(rl)])[lane], &c_buf[gi]);
            h_out[gi] = lds[rl * 64 + lane];
        }
    }
    // ---- proj store: out_{t-1} ----
    if (my_proj && t > 0 && p < INP) {
#pragma unroll
        for (int mf = 0; mf < 8; ++mf)
#pragma unroll
            for (int j = 0; j < 4; ++j) {
                int row = m0 + qr * 128 + mf * 16 + s4 * 4 + j;
                __builtin_nontemporal_store(
                    pacc[mf][j], &outp[((size_t)row * TT + (t - 1)) * INP + p]);
            }
    }
}

// ---------------- launch ----------------
extern "C" void kernel_launch(void* const* d_in, const int* in_sizes, int n_in,
                              void* d_out, int out_size, void* d_ws, size_t ws_size,
                              hipStream_t stream)
{
    const float* x    = (const float*)d_in[0];
    const float* Wih  = (const float*)d_in[1];
    const float* Whh  = (const float*)d_in[2];
    const float* bih  = (const float*)d_in[3];
    const float* bhh  = (const float*)d_in[4];
    const float* Wlin = (const float*)d_in[5];
    const float* blin = (const float*)d_in[6];
    float* out = (float*)d_out;

    char* ws = (char*)d_ws;
    u16* hb0     = (u16*)(ws);                     //  8,388,608 B
    u16* hb1     = (u16*)(ws +  8388608);          //  8,388,608 B
    u16* xpad64  = (u16*)(ws + 16777216);          // 10,485,760 B (20 t-slots x 64)
    u16* wperm   = (u16*)(ws + 27262976);          //  8,454,144 B (4128 x 1024)
    u16* wx64    = (u16*)(ws + 35717120);          //    528,384 B (4128 x 64)
    float* bias  = (float*)(ws + 36245504);        //     16,384 B

    float* h_fin = out + (size_t)BB * TT * INP;    // h_fin region
    float* c_buf = h_fin + (size_t)BB * HH;        // c_fin region = c state

    hipFuncSetAttribute((const void*)lstm_step,
                        hipFuncAttributeMaxDynamicSharedMemorySize, LDS_BYTES);

    hipMemsetAsync(hb0, 0, (size_t)BB * HH * sizeof(u16), stream);
    hipMemsetAsync(c_buf, 0, (size_t)BB * HH * sizeof(float), stream);
    hipMemsetAsync((char*)xpad64 + (size_t)19 * BB * 64 * 2, 0, BB * 64 * 2, stream);

    prep_wperm<<<2064, 256, 0, stream>>>(Whh, Wlin, wperm);
    prep_wx64<<<1032, 256, 0, stream>>>(Wih, wx64);
    prep_bias<<<16, 256, 0, stream>>>(bih, bhh, bias);
    prep_x64<<<19456, 256, 0, stream>>>(x, xpad64);

    for (int t = 0; t < TT; ++t) {
        const u16* hin = (t & 1) ? hb1 : hb0;
        u16* hout = (t & 1) ? hb0 : hb1;
        lstm_step<<<256, 512, LDS_BYTES, stream>>>(
            hin, hout, c_buf, wperm, wx64, bias, xpad64, blin, out,
            h_fin, t, (t == TT - 1) ? 1 : 0, 0);
    }
    // tail: out_18 = h_19 @ W_lin^T + b_lin  (h_19 is in hb1 after t=18)
    lstm_step<<<16, 512, LDS_BYTES, stream>>>(
        hb1, hb0, c_buf, wperm, wx64, bias, xpad64, blin, out,
        h_fin, TT, 0, 1);
}

// Round 14
// 1015.994 us; speedup vs baseline: 1.4213x; 1.0108x over previous
//
#include <hip/hip_runtime.h>
#include <hip/hip_bf16.h>

typedef unsigned short u16;
typedef __attribute__((ext_vector_type(8))) __bf16 bf16x8;
typedef __attribute__((ext_vector_type(8))) short short8;
typedef __attribute__((ext_vector_type(4))) float f32x4;

#define BB 4096
#define TT 19
#define INP 17
#define HH 1024
#define NE 4128          // 4096 permuted gate entries + 32 proj rows
#define NT_PROJ 15       // proj rows are staged/used by nt==15 blocks

// dynamic LDS map (u16 units): A dbuf 2x16384, B dbuf 2x16384, P dbuf 2x2048
// epilogue reuse: h tile [256][64] u16 -> A0 region; c tile [256][64] f32 ->
// A1 (rows 0..127) + B1 (rows 128..255) regions.
#define ABASE(b) ((b) * 16384)
#define BBASE(b) (32768 + (b) * 16384)
#define PBASE(b) (65536 + (b) * 2048)
#define LDS_BYTES 139264

#define FENCE asm volatile("" ::: "memory")

__device__ __forceinline__ u16 f2bfu(float f) {
    __hip_bfloat16 b = __float2bfloat16(f);
    return __builtin_bit_cast(unsigned short, b);
}
__device__ __forceinline__ float fast_sigmoid(float x) {
    return 1.f / (1.f + __expf(-x));
}
__device__ __forceinline__ float fast_tanh(float x) {
    float e = __expf(2.f * x);
    return (e - 1.f) / (e + 1.f);
}
__device__ __forceinline__ bf16x8 ldfrag(const u16* p) {
    return __builtin_bit_cast(bf16x8, *(const short8*)p);
}
// c-tile row base in u16 units (A1 for rows 0..127, B1 for 128..255)
__device__ __forceinline__ int cBase(int row) {
    return row < 128 ? 16384 + row * 128 : 49152 + (row - 128) * 128;
}
// async 16B global -> LDS (linear dest = wave base + lane*16)
__device__ __forceinline__ void cp16(const u16* l, const void* g) {
    __builtin_amdgcn_global_load_lds(
        (const __attribute__((address_space(1))) unsigned int*)g,
        (__attribute__((address_space(3))) unsigned int*)l, 16, 0, 0);
}

// ---------------- prep kernels ----------------
// wperm[NE][HH]: entry r of tile nt -> gate (r>>4)&3, hcol nt*64+(r>>6)*16+(r&15);
// rows 4096..4127 = W_lin rows (17 real + zero pad). grid MUST be 2064.
__global__ void prep_wperm(const float* __restrict__ Whh, const float* __restrict__ Wlin,
                           u16* __restrict__ wperm) {
    size_t idx = ((size_t)blockIdx.x * 256 + threadIdx.x) * 8;
    int R = (int)(idx >> 10);
    int k = (int)(idx & 1023);
    const float* src = nullptr;
    if (R < 4096) {
        int nt = R >> 8, r = R & 255;
        int qn = r >> 6, nf = (r >> 4) & 3, cj = r & 15;
        int hcol = nt * 64 + qn * 16 + cj;
        src = Whh + ((size_t)(nf * HH + hcol)) * HH + k;
    } else if (R - 4096 < INP) {
        src = Wlin + (size_t)(R - 4096) * HH + k;
    }
#pragma unroll
    for (int e = 0; e < 8; ++e) wperm[idx + e] = src ? f2bfu(src[e]) : (u16)0;
}

// wx64[NE][64]: same row permutation of W_ih, K padded 17->64. grid 1032.
__global__ void prep_wx64(const float* __restrict__ Wih, u16* __restrict__ wx64) {
    int idx = blockIdx.x * 256 + threadIdx.x;
    int R = idx >> 6, k = idx & 63;
    u16 v = 0;
    if (R < 4096 && k < INP) {
        int nt = R >> 8, r = R & 255;
        int qn = r >> 6, nf = (r >> 4) & 3, cj = r & 15;
        int hcol = nt * 64 + qn * 16 + cj;
        v = f2bfu(Wih[(size_t)(nf * HH + hcol) * INP + k]);
    }
    wx64[idx] = v;
}

// bias[4096] = b_ih + b_hh. grid 16.
__global__ void prep_bias(const float* __restrict__ bih, const float* __restrict__ bhh,
                          float* __restrict__ bias) {
    int idx = blockIdx.x * 256 + threadIdx.x;
    bias[idx] = bih[idx] + bhh[idx];
}

// xpad64[t][b][64], K padded 17->64. grid 19456 (covers t<19; slot 19 memset).
__global__ void prep_x64(const float* __restrict__ x, u16* __restrict__ xpad) {
    int idx = blockIdx.x * 256 + threadIdx.x;
    int c = idx & 63;
    int rb = idx >> 6;
    int t = rb >> 12;
    int b = rb & 4095;
    xpad[idx] = (c < INP) ? f2bfu(x[((size_t)b * TT + t) * INP + c]) : (u16)0;
}

// ------- fused step kernel: 256x256, BK=64, counted-vmcnt pipeline -------
// grid 256 = 16 mt x 16 nt (XCD 2D-chunked), 512 threads = 8 waves (2qr x 4qn).
// NK K-tiles (tile 0 = x/wx64; tiles 1..16 = h/wperm). t==0 runs NK=1 (h==0).
// Double-buffered, counted vmcnt (never 0 in steady loop). Last tile also
// stages c_old into the free LDS halves (overlapped). Epilogue: cell in regs
// -> h/c tiles in LDS -> fully-coalesced row-major stores; c stores PLAIN
// (L2/L3-resident for the next launch; NT would force an HBM round-trip).
__global__ __launch_bounds__(512, 2) void lstm_step(
    const u16* __restrict__ h_in, u16* __restrict__ h_out,
    float* __restrict__ c_buf, const u16* __restrict__ wperm,
    const u16* __restrict__ wx64, const float* __restrict__ bias,
    const u16* __restrict__ xpad64, const float* __restrict__ blin,
    float* __restrict__ outp, float* __restrict__ h_fin,
    int t, int is_last, int tail)
{
    extern __shared__ u16 lds[];

    const int tid = threadIdx.x;
    const int lane = tid & 63;
    const int wv = tid >> 6;
    const int qr = wv >> 2, qn = wv & 3;
    const int r16 = lane & 15, s4 = lane >> 4;

    int mt, nt;
    if (tail) { mt = blockIdx.x; nt = NT_PROJ; }
    else {
        const int xcd = blockIdx.x & 7, local = blockIdx.x >> 3;
        mt = (xcd >> 2) * 8 + (local & 7);
        nt = (xcd & 3) * 4 + (local >> 3);
    }
    const int m0 = mt * 256;
    const size_t R0 = (size_t)nt * 256;
    const bool my_proj = (nt == NT_PROJ) && (qn < 2);
    const int NK = (tail || t > 0) ? 17 : 1;   // t==0: gates = x@Wih + b only

    // staging: 4 dest slots per thread (A and B each); slot d -> row d>>3,
    // physical 16B chunk d&7 holds logical chunk gc = (d&7)^(row&7).
    int srow[4], sgc[4];
#pragma unroll
    for (int i = 0; i < 4; ++i) {
        int d = tid + i * 512;
        srow[i] = d >> 3;
        sgc[i] = (d & 7) ^ (srow[i] & 7);
    }
    const u16* hA[4];
    const u16* wB[4];
#pragma unroll
    for (int i = 0; i < 4; ++i) {
        hA[i] = h_in + (size_t)(m0 + srow[i]) * HH + sgc[i] * 8;
        wB[i] = wperm + (R0 + srow[i]) * HH + sgc[i] * 8;
    }
    const int prow = (tid >> 3) & 31;
    const int pgc = (tid & 7) ^ (prow & 7);
    const u16* wP = wperm + (size_t)(4096 + prow) * HH + pgc * 8;

    // fragment offsets for kk=0; kk=1 is ^32
    int aoff[8], boff[4], poff;
#pragma unroll
    for (int mf = 0; mf < 8; ++mf) {
        int r = qr * 128 + mf * 16 + r16;
        aoff[mf] = r * 64 + ((s4 ^ (r & 7)) * 8);
    }
#pragma unroll
    for (int nf = 0; nf < 4; ++nf) {
        int r = qn * 64 + nf * 16 + r16;
        boff[nf] = r * 64 + ((s4 ^ (r & 7)) * 8);
    }
    {
        int r = qn * 16 + r16;
        poff = r * 64 + ((s4 ^ (r & 7)) * 8);
    }

    // acc init with bias
    f32x4 acc[8][4];
    const int n = nt * 64 + qn * 16 + r16;
    if (!tail) {
#pragma unroll
        for (int nf = 0; nf < 4; ++nf) {
            float bv = bias[nf * HH + n];
#pragma unroll
            for (int mf = 0; mf < 8; ++mf) acc[mf][nf] = (f32x4){bv, bv, bv, bv};
        }
    }
    f32x4 pacc[8];
    const int p = qn * 16 + r16;
    if (my_proj) {
        float pv = (p < INP) ? blin[p] : 0.f;
#pragma unroll
        for (int mf = 0; mf < 8; ++mf) pacc[mf] = (f32x4){pv, pv, pv, pv};
    }

    // ---- prologue: stage tile 0 (x | wx64 | P) ----
    const u16* xA = xpad64 + ((size_t)t * BB + m0) * 64;
#pragma unroll
    for (int i = 0; i < 4; ++i)
        cp16(&lds[ABASE(0) + (tid + i * 512) * 8], xA + (size_t)srow[i] * 64 + sgc[i] * 8);
#pragma unroll
    for (int i = 0; i < 4; ++i)
        cp16(&lds[BBASE(0) + (tid + i * 512) * 8], wx64 + (R0 + srow[i]) * 64 + sgc[i] * 8);
    if (wv < 4) cp16(&lds[PBASE(0) + tid * 8], wP);

    // ---- pipeline over NK K-tiles ----
    for (int j = 0; j < NK; ++j) {
        const int cb = j & 1, nb = cb ^ 1;
        if (j < NK - 1) {
            const int ko = j * 64;        // h K-offset of tile j+1
#pragma unroll
            for (int i = 0; i < 4; ++i)
                cp16(&lds[ABASE(nb) + (tid + i * 512) * 8], hA[i] + ko);
#pragma unroll
            for (int i = 0; i < 4; ++i)
                cp16(&lds[BBASE(nb) + (tid + i * 512) * 8], wB[i] + ko);
            if (wv < 4) {
                cp16(&lds[PBASE(nb) + tid * 8], wP + ko);
                asm volatile("s_waitcnt vmcnt(9)" ::: "memory");
            } else {
                asm volatile("s_waitcnt vmcnt(8)" ::: "memory");
            }
        } else if (!tail) {
            // last tile: stage c_old (256x64 f32) into A1+B1 regions, coalesced
#pragma unroll
            for (int i = 0; i < 8; ++i) {
                const int s = tid + i * 512;
                const int crow = s >> 4, cch = s & 15;
                const u16* dst = (i < 4) ? &lds[16384 + s * 8] : &lds[32768 + s * 8];
                cp16(dst, c_buf + (size_t)(m0 + crow) * HH + nt * 64 + cch * 4);
            }
            asm volatile("s_waitcnt vmcnt(8)" ::: "memory");
        } else {
            asm volatile("s_waitcnt vmcnt(0)" ::: "memory");
        }
        __builtin_amdgcn_s_barrier();
        FENCE;

        const int cbA = ABASE(cb), cbB = BBASE(cb), cbP = PBASE(cb);
        const bool do_p = my_proj && (j > 0);
        __builtin_amdgcn_s_setprio(1);
#pragma unroll
        for (int kk = 0; kk < 2; ++kk) {
            const int kx = kk * 32;
            bf16x8 b[4];
            if (!tail) {
#pragma unroll
                for (int nf = 0; nf < 4; ++nf)
                    b[nf] = ldfrag(&lds[cbB + (boff[nf] ^ kx)]);
            }
            bf16x8 pb;
            if (do_p) pb = ldfrag(&lds[cbP + (poff ^ kx)]);
#pragma unroll
            for (int h2 = 0; h2 < 2; ++h2) {
                bf16x8 a[4];
#pragma unroll
                for (int i = 0; i < 4; ++i)
                    a[i] = ldfrag(&lds[cbA + (aoff[h2 * 4 + i] ^ kx)]);
                if (!tail) {
#pragma unroll
                    for (int nf = 0; nf < 4; ++nf)
#pragma unroll
                        for (int i = 0; i < 4; ++i)
                            acc[h2 * 4 + i][nf] = __builtin_amdgcn_mfma_f32_16x16x32_bf16(
                                a[i], b[nf], acc[h2 * 4 + i][nf], 0, 0, 0);
                }
                if (do_p) {
#pragma unroll
                    for (int i = 0; i < 4; ++i)
                        pacc[h2 * 4 + i] = __builtin_amdgcn_mfma_f32_16x16x32_bf16(
                            a[i], pb, pacc[h2 * 4 + i], 0, 0, 0);
                }
            }
        }
        __builtin_amdgcn_s_setprio(0);
        FENCE;
        __builtin_amdgcn_s_barrier();
        FENCE;
    }

    // ---- epilogue: cell in regs -> LDS tiles -> coalesced stores ----
    if (!tail) {
        asm volatile("s_waitcnt vmcnt(0)" ::: "memory");
        __syncthreads();                  // c_old tile resident for all
        const int cl = qn * 16 + r16;     // col 0..63 within tile
#pragma unroll
        for (int mf = 0; mf < 8; ++mf)
#pragma unroll
            for (int j = 0; j < 4; ++j) {
                int rl = qr * 128 + mf * 16 + s4 * 4 + j;
                float iv = fast_sigmoid(acc[mf][0][j]);
                float fv = fast_sigmoid(acc[mf][1][j]);
                float gv = fast_tanh(acc[mf][2][j]);
                float ov = fast_sigmoid(acc[mf][3][j]);
                float* crow = (float*)&lds[cBase(rl)];
                float cold = crow[cl];
                float cnew = fv * cold + iv * gv;
                float hnew = ov * fast_tanh(cnew);
                crow[cl] = cnew;                       // c tile in-place
                lds[rl * 64 + cl] = f2bfu(hnew);       // h tile (A0 region)
                if (is_last)
                    __builtin_nontemporal_store(
                        hnew, &h_fin[(size_t)(m0 + rl) * HH + n]);
            }
        __syncthreads();
        // coalesced stores: wave wv owns rows wv*32..wv*32+31; lane = col.
        // c stores PLAIN: stays L2/L3-resident for next launch's c staging.
#pragma unroll 4
        for (int r = 0; r < 32; ++r) {
            const int rl = wv * 32 + r;
            const size_t gi = (size_t)(m0 + rl) * HH + nt * 64 + lane;
            c_buf[gi] = ((float*)&lds[cBase(rl)])[lane];
            h_out[gi] = lds[rl * 64 + lane];
        }
    }
    // ---- proj store: out_{t-1} ----
    if (my_proj && t > 0 && p < INP) {
#pragma unroll
        for (int mf = 0; mf < 8; ++mf)
#pragma unroll
            for (int j = 0; j < 4; ++j) {
                int row = m0 + qr * 128 + mf * 16 + s4 * 4 + j;
                __builtin_nontemporal_store(
                    pacc[mf][j], &outp[((size_t)row * TT + (t - 1)) * INP + p]);
            }
    }
}

// ---------------- launch ----------------
extern "C" void kernel_launch(void* const* d_in, const int* in_sizes, int n_in,
                              void* d_out, int out_size, void* d_ws, size_t ws_size,
                              hipStream_t stream)
{
    const float* x    = (const float*)d_in[0];
    const float* Wih  = (const float*)d_in[1];
    const float* Whh  = (const float*)d_in[2];
    const float* bih  = (const float*)d_in[3];
    const float* bhh  = (const float*)d_in[4];
    const float* Wlin = (const float*)d_in[5];
    const float* blin = (const float*)d_in[6];
    float* out = (float*)d_out;

    char* ws = (char*)d_ws;
    u16* hb0     = (u16*)(ws);                     //  8,388,608 B
    u16* hb1     = (u16*)(ws +  8388608);          //  8,388,608 B
    u16* xpad64  = (u16*)(ws + 16777216);          // 10,485,760 B (20 t-slots x 64)
    u16* wperm   = (u16*)(ws + 27262976);          //  8,454,144 B (4128 x 1024)
    u16* wx64    = (u16*)(ws + 35717120);          //    528,384 B (4128 x 64)
    float* bias  = (float*)(ws + 36245504);        //     16,384 B

    float* h_fin = out + (size_t)BB * TT * INP;    // h_fin region
    float* c_buf = h_fin + (size_t)BB * HH;        // c_fin region = c state

    hipFuncSetAttribute((const void*)lstm_step,
                        hipFuncAttributeMaxDynamicSharedMemorySize, LDS_BYTES);

    hipMemsetAsync(c_buf, 0, (size_t)BB * HH * sizeof(float), stream);
    hipMemsetAsync((char*)xpad64 + (size_t)19 * BB * 64 * 2, 0, BB * 64 * 2, stream);

    prep_wperm<<<2064, 256, 0, stream>>>(Whh, Wlin, wperm);
    prep_wx64<<<1032, 256, 0, stream>>>(Wih, wx64);
    prep_bias<<<16, 256, 0, stream>>>(bih, bhh, bias);
    prep_x64<<<19456, 256, 0, stream>>>(x, xpad64);

    for (int t = 0; t < TT; ++t) {
        const u16* hin = (t & 1) ? hb1 : hb0;
        u16* hout = (t & 1) ? hb0 : hb1;
        lstm_step<<<256, 512, LDS_BYTES, stream>>>(
            hin, hout, c_buf, wperm, wx64, bias, xpad64, blin, out,
            h_fin, t, (t == TT - 1) ? 1 : 0, 0);
    }
    // tail: out_18 = h_19 @ W_lin^T + b_lin  (h_19 is in hb1 after t=18)
    lstm_step<<<16, 512, LDS_BYTES, stream>>>(
        hb1, hb0, c_buf, wperm, wx64, bias, xpad64, blin, out,
        h_fin, TT, 0, 1);
}